// Round 1
// baseline (1051.519 us; speedup 1.0000x reference)
//
#include <hip/hip_runtime.h>

// SelfAttention: x[2,2048,5120] -> QKV proj -> RoPE -> causal GQA attention -> out proj
// All matmuls in bf16 MFMA (16x16x32), f32 accum. Tolerance is bf16-grade (0.148 absmax).

typedef unsigned short u16;
typedef __bf16 bf16x8 __attribute__((ext_vector_type(8)));
typedef float f32x4 __attribute__((ext_vector_type(4)));

__device__ __forceinline__ u16 f2bf(float f) {
  unsigned u = __builtin_bit_cast(unsigned, f);
  u += 0x7fff + ((u >> 16) & 1);   // RNE
  return (u16)(u >> 16);
}
__device__ __forceinline__ float bf2f(u16 h) {
  unsigned u = ((unsigned)h) << 16;
  return __builtin_bit_cast(float, u);
}

__device__ __forceinline__ void gload_lds16(const u16* g, u16* lds) {
  __builtin_amdgcn_global_load_lds(
      (const __attribute__((address_space(1))) void*)g,
      (__attribute__((address_space(3))) void*)lds, 16, 0, 0);
}

__device__ __forceinline__ f32x4 mfma16(bf16x8 a, bf16x8 b, f32x4 c) {
  return __builtin_amdgcn_mfma_f32_16x16x32_bf16(a, b, c, 0, 0, 0);
}

// ---------------- f32 -> bf16 bulk convert (vectorized) ----------------
__global__ __launch_bounds__(256) void cvt_kernel(const float4* __restrict__ in,
                                                  uint2* __restrict__ out, int n4) {
  int i = blockIdx.x * blockDim.x + threadIdx.x;
  if (i >= n4) return;
  float4 v = in[i];
  unsigned lo = (unsigned)f2bf(v.x) | ((unsigned)f2bf(v.y) << 16);
  unsigned hi = (unsigned)f2bf(v.z) | ((unsigned)f2bf(v.w) << 16);
  out[i] = make_uint2(lo, hi);
}

// ---------------- RoPE in-place on bf16 [*, nheads, 64 pairs] ----------------
__global__ __launch_bounds__(256) void rope_kernel(u16* __restrict__ t,
                                                   const float* __restrict__ fcos,
                                                   const float* __restrict__ fsin,
                                                   int hsh, float scale, int total) {
  int idx = blockIdx.x * blockDim.x + threadIdx.x;
  if (idx >= total) return;
  int j = idx & 63;
  int s = (idx >> (6 + hsh)) & 2047;
  float c = fcos[s * 64 + j], sn = fsin[s * 64 + j];
  unsigned* p = (unsigned*)(t + (size_t)idx * 2);
  unsigned v = *p;
  float tr = bf2f((u16)(v & 0xffffu)), ti = bf2f((u16)(v >> 16));
  float orr = (tr * c - ti * sn) * scale;
  float oi  = (tr * sn + ti * c) * scale;
  *p = (unsigned)f2bf(orr) | ((unsigned)f2bf(oi) << 16);
}

// ---------------- bf16 NT GEMM: C[M][N] = A[M][K] * B[N][K]^T ----------------
// 128x128 tile, BK=64, 4 waves (2x2 of 64x64), global_load_lds(16B), XOR-swizzled LDS.
// MODE 0: bf16 C[M][N]; MODE 1: f32 C[M][N]; MODE 2: bf16 transposed V store
//   (M=4096=b*2048+s rows, N=1024=h*128+d cols) -> VT[b][h][d][s] = [((b*8+h)*128+d)*2048+s]
template <int MODE>
__global__ __launch_bounds__(256) void gemm_bt(const u16* __restrict__ A,
                                               const u16* __restrict__ B,
                                               void* __restrict__ Cout,
                                               int M, int N, int K) {
  __shared__ u16 As[8192];  // [128][64] bf16, chunk c (16B) of row r stored at c^(r&7)
  __shared__ u16 Bs[8192];
  const int tid = threadIdx.x;
  const int lane = tid & 63, wave = tid >> 6;
  const int wm = wave >> 1, wn = wave & 1;
  const int m0 = blockIdx.y * 128, n0 = blockIdx.x * 128;
  const int lc = lane & 15, lg = lane >> 4;

  f32x4 acc[4][4] = {};
  const int sr = tid >> 3, sc = tid & 7;

  for (int kt = 0; kt < K; kt += 64) {
    __syncthreads();
#pragma unroll
    for (int q = 0; q < 4; ++q) {
      int r = q * 32 + sr;
      int cc = sc ^ (r & 7);
      gload_lds16(A + (size_t)(m0 + r) * K + kt + cc * 8, &As[q * 2048 + tid * 8]);
      gload_lds16(B + (size_t)(n0 + r) * K + kt + cc * 8, &Bs[q * 2048 + tid * 8]);
    }
    __syncthreads();
#pragma unroll
    for (int ks = 0; ks < 2; ++ks) {
      bf16x8 af[4], bfr[4];
#pragma unroll
      for (int m = 0; m < 4; ++m) {
        int r = wm * 64 + m * 16 + lc;
        int gc = ks * 4 + lg;
        af[m] = *(const bf16x8*)&As[r * 64 + ((gc ^ (r & 7)) * 8)];
      }
#pragma unroll
      for (int n = 0; n < 4; ++n) {
        int r = wn * 64 + n * 16 + lc;
        int gc = ks * 4 + lg;
        bfr[n] = *(const bf16x8*)&Bs[r * 64 + ((gc ^ (r & 7)) * 8)];
      }
#pragma unroll
      for (int m = 0; m < 4; ++m)
#pragma unroll
        for (int n = 0; n < 4; ++n)
          acc[m][n] = mfma16(af[m], bfr[n], acc[m][n]);
    }
  }

  // epilogue: C/D layout col=lane&15, row=(lane>>4)*4+i  [m89-verified]
#pragma unroll
  for (int m = 0; m < 4; ++m) {
#pragma unroll
    for (int n = 0; n < 4; ++n) {
#pragma unroll
      for (int i = 0; i < 4; ++i) {
        int gm = m0 + wm * 64 + m * 16 + lg * 4 + i;
        int gn = n0 + wn * 64 + n * 16 + lc;
        float v = acc[m][n][i];
        if (MODE == 0) {
          ((u16*)Cout)[(size_t)gm * N + gn] = f2bf(v);
        } else if (MODE == 1) {
          ((float*)Cout)[(size_t)gm * N + gn] = v;
        } else {
          size_t addr = ((size_t)((gm >> 11) * 8 + (gn >> 7)) * 128 + (gn & 127)) * 2048 +
                        (gm & 2047);
          ((u16*)Cout)[addr] = f2bf(v);
        }
      }
    }
  }
}

// ---------------- causal GQA flash attention ----------------
// grid (S/64, HQ, B), 256 thr = 4 waves; wave w owns q rows [q0+16w, q0+16w+16).
// Q pre-scaled by 1/sqrt(128) in RoPE. K [b,s,hkv,d]; V pre-transposed VT[b,hkv,d,s].
__global__ __launch_bounds__(256) void attn_kernel(const u16* __restrict__ Q,
                                                   const u16* __restrict__ Kg,
                                                   const u16* __restrict__ VT,
                                                   u16* __restrict__ AO) {
  __shared__ u16 Ks[8192];        // [kv 64][d 128], 256B rows, chunk ^ (r&15)
  __shared__ u16 VTs[8192];       // [d 128][kv 64], 128B rows, chunk ^ (r&7)
  __shared__ u16 P_lds[4][16 * 72];  // per-wave P [16][64], stride 72 (2-way free)
  const int tid = threadIdx.x, lane = tid & 63, w = tid >> 6;
  const int qt = blockIdx.x, h = blockIdx.y, b = blockIdx.z;
  const int hkv = h >> 2;
  const int q0 = qt * 64;
  const int lc = lane & 15, lg = lane >> 4;

  // Q fragments (A-operand): row=lane&15, k=(lane>>4)*8 (+32*ks)
  bf16x8 qf[4];
  {
    const size_t qrow = ((size_t)(b * 2048 + q0 + w * 16 + lc) * 32 + h) * 128;
#pragma unroll
    for (int ks = 0; ks < 4; ++ks) qf[ks] = *(const bf16x8*)&Q[qrow + ks * 32 + lg * 8];
  }

  f32x4 o[8] = {};
  float mrow[4], lrow[4];
#pragma unroll
  for (int i = 0; i < 4; ++i) { mrow[i] = -1e30f; lrow[i] = 0.f; }

  const int nsteps = qt + 1;
  const int ksr = tid >> 4, ksc = tid & 15;  // K staging: 16 chunks/row
  const int vsr = tid >> 3, vsc = tid & 7;   // VT staging: 8 chunks/row

  for (int step = 0; step < nsteps; ++step) {
    const int kv0 = step * 64;
    __syncthreads();  // everyone done reading Ks/VTs from previous step
#pragma unroll
    for (int qq = 0; qq < 4; ++qq) {  // K tile: 64 rows x 256B
      int r = qq * 16 + ksr;
      int cc = ksc ^ (r & 15);
      gload_lds16(Kg + ((size_t)(b * 2048 + kv0 + r) * 8 + hkv) * 128 + cc * 8,
                  &Ks[qq * 2048 + tid * 8]);
    }
#pragma unroll
    for (int qq = 0; qq < 4; ++qq) {  // VT tile: 128 rows x 128B
      int r = qq * 32 + vsr;
      int cc = vsc ^ (r & 7);
      gload_lds16(VT + ((size_t)(b * 8 + hkv) * 128 + r) * 2048 + kv0 + cc * 8,
                  &VTs[qq * 2048 + tid * 8]);
    }
    __syncthreads();  // drains vmcnt(0): tiles resident

    // QK^T: s[nf] covers kv cols nf*16+lc, q rows lg*4+i
    f32x4 s[4];
#pragma unroll
    for (int nf = 0; nf < 4; ++nf) s[nf] = f32x4{0.f, 0.f, 0.f, 0.f};
#pragma unroll
    for (int ks = 0; ks < 4; ++ks) {
#pragma unroll
      for (int nf = 0; nf < 4; ++nf) {
        int r = nf * 16 + lc;
        int gc = ks * 4 + lg;
        bf16x8 kf = *(const bf16x8*)&Ks[r * 128 + ((gc ^ (r & 15)) * 8)];
        s[nf] = mfma16(qf[ks], kf, s[nf]);
      }
    }

    // causal mask
#pragma unroll
    for (int nf = 0; nf < 4; ++nf) {
      int col = kv0 + nf * 16 + lc;
#pragma unroll
      for (int i = 0; i < 4; ++i) {
        int row = q0 + w * 16 + lg * 4 + i;
        if (col > row) s[nf][i] = -1e30f;
      }
    }

    // online softmax (row stats live in all 16 lanes of each group)
#pragma unroll
    for (int i = 0; i < 4; ++i) {
      float t = fmaxf(fmaxf(s[0][i], s[1][i]), fmaxf(s[2][i], s[3][i]));
#pragma unroll
      for (int d = 1; d < 16; d <<= 1) t = fmaxf(t, __shfl_xor(t, d, 64));
      float mn = fmaxf(mrow[i], t);
      float alpha = __expf(mrow[i] - mn);
      mrow[i] = mn;
      float rs = 0.f;
#pragma unroll
      for (int nf = 0; nf < 4; ++nf) {
        float p = __expf(s[nf][i] - mn);
        s[nf][i] = p;
        rs += p;
      }
#pragma unroll
      for (int d = 1; d < 16; d <<= 1) rs += __shfl_xor(rs, d, 64);
      lrow[i] = lrow[i] * alpha + rs;
#pragma unroll
      for (int nfd = 0; nfd < 8; ++nfd) o[nfd][i] *= alpha;
    }

    // P -> LDS (bf16), then read back as A-fragments (same wave only)
#pragma unroll
    for (int nf = 0; nf < 4; ++nf)
#pragma unroll
      for (int i = 0; i < 4; ++i)
        P_lds[w][(lg * 4 + i) * 72 + nf * 16 + lc] = f2bf(s[nf][i]);
    asm volatile("s_waitcnt lgkmcnt(0)" ::: "memory");

    bf16x8 pa[2];
#pragma unroll
    for (int ksv = 0; ksv < 2; ++ksv)
      pa[ksv] = *(const bf16x8*)&P_lds[w][lc * 72 + ksv * 32 + lg * 8];

    // PV: o[nfd] covers d cols nfd*16+lc
#pragma unroll
    for (int nfd = 0; nfd < 8; ++nfd) {
#pragma unroll
      for (int ksv = 0; ksv < 2; ++ksv) {
        int r = nfd * 16 + lc;
        int gc = ksv * 4 + lg;
        bf16x8 vf = *(const bf16x8*)&VTs[r * 64 + ((gc ^ (r & 7)) * 8)];
        o[nfd] = mfma16(pa[ksv], vf, o[nfd]);
      }
    }
  }

  // normalize + store AO [b, s, h, d] bf16
#pragma unroll
  for (int i = 0; i < 4; ++i) lrow[i] = 1.0f / lrow[i];
#pragma unroll
  for (int nfd = 0; nfd < 8; ++nfd)
#pragma unroll
    for (int i = 0; i < 4; ++i) {
      int row = q0 + w * 16 + lg * 4 + i;
      AO[((size_t)(b * 2048 + row) * 32 + h) * 128 + nfd * 16 + lc] =
          f2bf(o[nfd][i] * lrow[i]);
    }
}

extern "C" void kernel_launch(void* const* d_in, const int* in_sizes, int n_in,
                              void* d_out, int out_size, void* d_ws, size_t ws_size,
                              hipStream_t stream) {
  const float* x    = (const float*)d_in[0];
  const float* fcos = (const float*)d_in[1];
  const float* fsin = (const float*)d_in[2];
  const float* wq   = (const float*)d_in[3];
  const float* wk   = (const float*)d_in[4];
  const float* wv   = (const float*)d_in[5];
  const float* wo   = (const float*)d_in[6];
  float* out = (float*)d_out;

  char* ws = (char*)d_ws;
  u16* xb  = (u16*)(ws + 0);             // 41,943,040 B  (x bf16)   -> later AO
  u16* wqb = (u16*)(ws + 41943040ull);   // 41,943,040 B  (wq bf16)  -> later wo bf16
  u16* wkb = (u16*)(ws + 83886080ull);   // 10,485,760 B
  u16* wvb = (u16*)(ws + 94371840ull);   // 10,485,760 B
  u16* Qb  = (u16*)(ws + 104857600ull);  // 33,554,432 B
  u16* Kb  = (u16*)(ws + 138412032ull);  //  8,388,608 B
  u16* VTb = (u16*)(ws + 146800640ull);  //  8,388,608 B  (total 155,189,248 B)
  u16* AOb = xb;
  u16* wob = wqb;

  auto cvt = [&](const float* src, u16* dst, int nelem) {
    int n4 = nelem / 4;
    cvt_kernel<<<dim3((n4 + 255) / 256), dim3(256), 0, stream>>>((const float4*)src,
                                                                 (uint2*)dst, n4);
  };
  cvt(x, xb, 2 * 2048 * 5120);
  cvt(wq, wqb, 4096 * 5120);
  cvt(wk, wkb, 1024 * 5120);
  cvt(wv, wvb, 1024 * 5120);

  dim3 blk(256);
  gemm_bt<0><<<dim3(32, 32), blk, 0, stream>>>(xb, wqb, Qb, 4096, 4096, 5120);
  gemm_bt<0><<<dim3(8, 32), blk, 0, stream>>>(xb, wkb, Kb, 4096, 1024, 5120);
  gemm_bt<2><<<dim3(8, 32), blk, 0, stream>>>(xb, wvb, VTb, 4096, 1024, 5120);

  cvt(wo, wob, 5120 * 4096);  // wq dead now; reuse its slot

  const float qscale = 0.08838834764831845f;  // 1/sqrt(128), folded into Q
  rope_kernel<<<dim3(8388608 / 256), blk, 0, stream>>>(Qb, fcos, fsin, 5, qscale, 8388608);
  rope_kernel<<<dim3(2097152 / 256), blk, 0, stream>>>(Kb, fcos, fsin, 3, 1.0f, 2097152);

  attn_kernel<<<dim3(32, 32, 2), blk, 0, stream>>>(Qb, Kb, VTb, AOb);

  gemm_bt<1><<<dim3(40, 32), blk, 0, stream>>>(AOb, wob, out, 4096, 5120, 4096);
}